// Round 18
// baseline (472.240 us; speedup 1.0000x reference)
//
#include <hip/hip_runtime.h>
#include <hip/hip_bf16.h>
#include <math.h>

#define DEVINL static __device__ __forceinline__

typedef _Float16 f16x8 __attribute__((ext_vector_type(8)));
typedef _Float16 f16x4 __attribute__((ext_vector_type(4)));
typedef float f32x4 __attribute__((ext_vector_type(4)));
typedef float f32x16 __attribute__((ext_vector_type(16)));

// B=2, T=2048, C=1024, H=16, D=64
constexpr int TT = 2048, CC = 1024, HH = 16, DD = 64;
constexpr int HALF_Y = 2 * TT * CC;
constexpr int HALF_L = 2 * HH * TT;

DEVINL void gload_lds16(const void* g, void* s) {
  __builtin_amdgcn_global_load_lds(
      (const __attribute__((address_space(1))) void*)g,
      (__attribute__((address_space(3))) void*)s, 16, 0, 0);
}

DEVINL unsigned pkrtz(float a, float b) {
  typedef __fp16 hf2 __attribute__((ext_vector_type(2)));
  union { hf2 h; unsigned u; } c;
  c.h = __builtin_amdgcn_cvt_pkrtz(a, b);
  return c.u;
}

DEVINL float fast_gelu(float v) {
  float z = v * (2.302208214f + 0.102945116f * v * v);
  return v * __builtin_amdgcn_rcpf(1.0f + exp2f(-z));
}

DEVINL int xcd_swizzle(int lid, int n) {
  int cpx = n >> 3;  // all grids are %8 == 0
  return (lid & 7) * cpx + (lid >> 3);
}

// ---- Fused: 4 weight transposes (fp32 [K,N] -> fp16 [N,K]) + LN1 + flag zero ----
DEVINL void transpose_tile(const float* in, _Float16* out, int K, int N,
                           int bx, int by, int tid) {
  __shared__ float tile[32][33];
  int n0 = bx * 32, k0 = by * 32;
  int tx = tid & 31, ty = tid >> 5;
  #pragma unroll
  for (int i = 0; i < 32; i += 8)
    tile[ty + i][tx] = in[(size_t)(k0 + ty + i) * N + n0 + tx];
  __syncthreads();
  #pragma unroll
  for (int i = 0; i < 32; i += 8)
    out[(size_t)(n0 + ty + i) * K + k0 + tx] = (_Float16)tile[tx][ty + i];
}

DEVINL void ln_row(const float* x, const float* g, const float* bta,
                   _Float16* out, int row, int t) {
  float4 v = ((const float4*)(x + (size_t)row * CC))[t];
  float s = v.x + v.y + v.z + v.w;
  float s2 = v.x * v.x + v.y * v.y + v.z * v.z + v.w * v.w;
  #pragma unroll
  for (int o = 32; o >= 1; o >>= 1) { s += __shfl_xor(s, o); s2 += __shfl_xor(s2, o); }
  __shared__ float ss[4], ssq[4];
  int w = t >> 6;
  if ((t & 63) == 0) { ss[w] = s; ssq[w] = s2; }
  __syncthreads();
  s = ss[0] + ss[1] + ss[2] + ss[3];
  s2 = ssq[0] + ssq[1] + ssq[2] + ssq[3];
  float mu = s * (1.0f / CC);
  float rs = rsqrtf(s2 * (1.0f / CC) - mu * mu + 1e-5f);
  float4 gv = ((const float4*)g)[t];
  float4 bv = ((const float4*)bta)[t];
  f16x4 o4;
  o4[0] = (_Float16)((v.x - mu) * rs * gv.x + bv.x);
  o4[1] = (_Float16)((v.y - mu) * rs * gv.y + bv.y);
  o4[2] = (_Float16)((v.z - mu) * rs * gv.z + bv.z);
  o4[3] = (_Float16)((v.w - mu) * rs * gv.w + bv.w);
  ((f16x4*)(out + (size_t)row * CC))[t] = o4;
}

__global__ __launch_bounds__(256) void prep_all(
    const float* __restrict__ w_qkv, const float* __restrict__ w_proj,
    const float* __restrict__ w_fc, const float* __restrict__ w_out,
    const float* __restrict__ x, const float* __restrict__ ln1_g,
    const float* __restrict__ ln1_b,
    _Float16* __restrict__ wqkv_t, _Float16* __restrict__ wproj_t,
    _Float16* __restrict__ wfc_t, _Float16* __restrict__ wout_t,
    _Float16* __restrict__ h1, int* __restrict__ flags) {
  int lid = blockIdx.x, t = threadIdx.x;
  if (lid == 0) { flags[t] = 0; flags[t + 256] = 0; }  // 512 pair flags
  if (lid < 3072) {
    transpose_tile(w_qkv, wqkv_t, 1024, 3072, lid % 96, lid / 96, t);
  } else if (lid < 4096) {
    int l = lid - 3072;
    transpose_tile(w_proj, wproj_t, 1024, 1024, l % 32, l / 32, t);
  } else if (lid < 8192) {
    int l = lid - 4096;
    transpose_tile(w_fc, wfc_t, 1024, 4096, l % 128, l / 128, t);
  } else if (lid < 12288) {
    int l = lid - 8192;
    transpose_tile(w_out, wout_t, 4096, 1024, l % 32, l / 32, t);
  } else {
    ln_row(x, ln1_g, ln1_b, h1, lid - 12288, t);
  }
}

__global__ __launch_bounds__(256) void ln_cast(
    const float* __restrict__ x, const float* __restrict__ g,
    const float* __restrict__ bta, _Float16* __restrict__ out) {
  ln_row(x, g, bta, out, blockIdx.x, threadIdx.x);
}

// ---- GEMM (verified structure): BK=64. 1D grid + XCD swizzle.
// BN=128: 4 waves 2x2 (64x64 each). BN=64: 4 waves 4x1 (32x64 each).
// DBUF=1: double-buffered LDS + counted vmcnt. EPI 1: GELU. EPI 2: +res fp32.
template <int EPI, int N, int K, int BN, int DBUF>
__global__ __launch_bounds__(256) void gemm_bt(
    const _Float16* __restrict__ A, const _Float16* __restrict__ Bt,
    const float* __restrict__ bias, const float* __restrict__ res,
    void* __restrict__ outp, int nbx) {
  constexpr int NWN = BN / 64;
  constexpr int MI = 2 * NWN;
  constexpr int NB = DBUF ? 2 : 1;
  constexpr int NLOADS = 4 + BN / 32;
  __shared__ __align__(16) _Float16 As[NB][128 * 64];
  __shared__ __align__(16) _Float16 Bs[NB][BN * 64];
  const int swz = xcd_swizzle(blockIdx.x, gridDim.x);
  const int bm0 = (swz / nbx) * 128, bn0 = (swz % nbx) * BN;
  const int t = threadIdx.x, w = t >> 6, l = t & 63, lg = l >> 4, lr = l & 15;
  const int wr = w / NWN, wc = w % NWN;
  const int srow = t >> 3, sc = t & 7;
  f32x4 acc[MI][4] = {};

  auto STAGE = [&](int bi, int k0) {
    #pragma unroll
    for (int q = 0; q < 4; ++q) {
      int row = q * 32 + srow;
      int gc = sc ^ (row & 7);  // inverse-swizzle global source (rule 21)
      gload_lds16(A + (size_t)(bm0 + row) * K + k0 + gc * 8, As[bi] + row * 64 + sc * 8);
    }
    #pragma unroll
    for (int q = 0; q < BN / 32; ++q) {
      int row = q * 32 + srow;
      int gc = sc ^ (row & 7);
      gload_lds16(Bt + (size_t)(bn0 + row) * K + k0 + gc * 8, Bs[bi] + row * 64 + sc * 8);
    }
  };
  auto COMPUTE = [&](const _Float16* Ac, const _Float16* Bc) {
    #pragma unroll
    for (int ks = 0; ks < 2; ++ks) {
      f16x8 af[MI], bfr[4];
      #pragma unroll
      for (int mi = 0; mi < MI; ++mi) {
        int row = wr * (16 * MI) + mi * 16 + lr;
        af[mi] = *(const f16x8*)(Ac + row * 64 + (((ks * 4 + lg) ^ (row & 7)) << 3));
      }
      #pragma unroll
      for (int ni = 0; ni < 4; ++ni) {
        int row = wc * 64 + ni * 16 + lr;
        bfr[ni] = *(const f16x8*)(Bc + row * 64 + (((ks * 4 + lg) ^ (row & 7)) << 3));
      }
      #pragma unroll
      for (int mi = 0; mi < MI; ++mi)
        #pragma unroll
        for (int ni = 0; ni < 4; ++ni)
          acc[mi][ni] = __builtin_amdgcn_mfma_f32_16x16x32_f16(af[mi], bfr[ni], acc[mi][ni], 0, 0, 0);
    }
  };

  if constexpr (DBUF) {
    STAGE(0, 0);
    int cur = 0;
    for (int k0 = 0; k0 < K; k0 += 64) {
      if (k0 + 64 < K) {
        STAGE(cur ^ 1, k0 + 64);
        asm volatile("s_waitcnt vmcnt(%0)" :: "i"(NLOADS) : "memory");
      } else {
        asm volatile("s_waitcnt vmcnt(0)" ::: "memory");
      }
      __builtin_amdgcn_s_barrier();
      COMPUTE(As[cur], Bs[cur]);
      __builtin_amdgcn_s_barrier();
      cur ^= 1;
    }
  } else {
    for (int k0 = 0; k0 < K; k0 += 64) {
      STAGE(0, k0);
      __syncthreads();
      COMPUTE(As[0], Bs[0]);
      __syncthreads();
    }
  }

  #pragma unroll
  for (int mi = 0; mi < MI; ++mi) {
    #pragma unroll
    for (int ni = 0; ni < 4; ++ni) {
      int gc = bn0 + wc * 64 + ni * 16 + lr;
      float bv = bias[gc];
      #pragma unroll
      for (int r = 0; r < 4; ++r) {
        int gr = bm0 + wr * (16 * MI) + mi * 16 + lg * 4 + r;
        float v = acc[mi][ni][r] + bv;
        if constexpr (EPI == 1) {
          ((_Float16*)outp)[(size_t)gr * N + gc] = (_Float16)fast_gelu(v);
        } else {
          ((float*)outp)[(size_t)gr * N + gc] = res[(size_t)gr * N + gc] + v;
        }
      }
    }
  }
}

// ---- QKV GEMM: BK=64 single-buffer, XCD swizzle ----
__global__ __launch_bounds__(256) void gemm_qkv(
    const _Float16* __restrict__ A, const _Float16* __restrict__ Bt,
    const float* __restrict__ bias,
    _Float16* __restrict__ qo, _Float16* __restrict__ ko,
    _Float16* __restrict__ vt) {
  __shared__ __align__(16) _Float16 As[128 * 64];
  __shared__ __align__(16) _Float16 Bs[128 * 64];
  const int swz = xcd_swizzle(blockIdx.x, gridDim.x);
  const int bm0 = (swz / 24) * 128, bn0 = (swz % 24) * 128;
  const int t = threadIdx.x, w = t >> 6, l = t & 63, lg = l >> 4, lr = l & 15;
  const int wr = w >> 1, wc = w & 1;
  const int srow = t >> 3, sc = t & 7;
  f32x4 acc[4][4] = {};
  for (int k0 = 0; k0 < 1024; k0 += 64) {
    #pragma unroll
    for (int q = 0; q < 4; ++q) {
      int row = q * 32 + srow;
      int gc = sc ^ (row & 7);
      gload_lds16(A + (size_t)(bm0 + row) * 1024 + k0 + gc * 8, As + row * 64 + sc * 8);
      gload_lds16(Bt + (size_t)(bn0 + row) * 1024 + k0 + gc * 8, Bs + row * 64 + sc * 8);
    }
    __syncthreads();
    #pragma unroll
    for (int ks = 0; ks < 2; ++ks) {
      f16x8 af[4], bfr[4];
      #pragma unroll
      for (int mi = 0; mi < 4; ++mi) {
        int row = wr * 64 + mi * 16 + lr;
        af[mi] = *(const f16x8*)(As + row * 64 + (((ks * 4 + lg) ^ (row & 7)) << 3));
      }
      #pragma unroll
      for (int ni = 0; ni < 4; ++ni) {
        int row = wc * 64 + ni * 16 + lr;
        bfr[ni] = *(const f16x8*)(Bs + row * 64 + (((ks * 4 + lg) ^ (row & 7)) << 3));
      }
      #pragma unroll
      for (int mi = 0; mi < 4; ++mi)
        #pragma unroll
        for (int ni = 0; ni < 4; ++ni)
          acc[mi][ni] = __builtin_amdgcn_mfma_f32_16x16x32_f16(af[mi], bfr[ni], acc[mi][ni], 0, 0, 0);
    }
    __syncthreads();
  }
  const float QSCL = 0.125f * 1.44269504f;
  #pragma unroll
  for (int mi = 0; mi < 4; ++mi) {
    #pragma unroll
    for (int ni = 0; ni < 4; ++ni) {
      int gc = bn0 + wc * 64 + ni * 16 + lr;
      float bv = bias[gc];
      int sec = gc >> 10, cc = gc & 1023;
      #pragma unroll
      for (int r = 0; r < 4; ++r) {
        int gr = bm0 + wr * 64 + mi * 16 + lg * 4 + r;
        float v = acc[mi][ni][r] + bv;
        if (sec == 0) {
          qo[(size_t)gr * 1024 + cc] = (_Float16)(v * QSCL);
        } else if (sec == 1) {
          ko[(size_t)gr * 1024 + cc] = (_Float16)v;
        } else {
          int hh = cc >> 6, dd = cc & 63;
          int bb = gr >> 11, tk = gr & (TT - 1);
          vt[(((size_t)bb * HH + hh) * DD + dd) * TT + tk] = (_Float16)v;
        }
      }
    }
  }
}

// ---- Flash attention v8: v6 + fused split-KV combine (atomic last-finisher).
// Every block writes its fp16 partial + L, fences, bumps the pair flag; the
// second finisher reads the partner's partial and writes the final blend.
// Bit-deterministic: own contribution is fp16-rounded in-register, so the
// blend is identical regardless of finish order. ----
__global__ __launch_bounds__(256, 4) void flash_attn(
    const _Float16* __restrict__ qg, const _Float16* __restrict__ kg,
    const _Float16* __restrict__ vt, _Float16* __restrict__ yp,
    float* __restrict__ Lp, int* __restrict__ flags,
    _Float16* __restrict__ att) {
  const int qt0 = blockIdx.x * 128, h = blockIdx.y;
  const int b = blockIdx.z & 1, half = blockIdx.z >> 1;
  const int kvbeg = half * (TT / 2), kvend = kvbeg + TT / 2;
  const int t = threadIdx.x, w = t >> 6, l = t & 63;
  const int l31 = l & 31, hi = l >> 5;
  __shared__ __align__(16) _Float16 Ks[2][64 * 64];
  __shared__ __align__(16) _Float16 VTs[2][64 * 64];
  const int srow = t >> 3, sc = t & 7;
  const int gc0 = sc ^ (srow & 7) ^ ((srow >> 3) & 7);
  const int gc1 = sc ^ (srow & 7) ^ (((srow >> 3) + 4) & 7);
  const _Float16* kg_r = kg + ((size_t)b * TT + srow) * CC + h * DD;
  const _Float16* vt_r = vt + (((size_t)b * HH + h) * DD + srow) * TT;
  const int dst0 = srow * 64 + sc * 8;

  f16x8 qf[4];
  {
    const _Float16* qp = qg + ((size_t)(b * TT + qt0 + w * 32 + l31)) * CC + h * DD + hi * 8;
    #pragma unroll
    for (int ks = 0; ks < 4; ++ks) qf[ks] = *(const f16x8*)(qp + ks * 16);
  }
  const int rx = l31 & 7, ry = (l31 >> 3) & 7;
  int swk[2], swv[2];
  #pragma unroll
  for (int sub = 0; sub < 2; ++sub) swk[sub] = rx ^ ((sub * 4 + ry) & 7);
  swv[0] = rx ^ ry;
  swv[1] = rx ^ ((4 + ry) & 7);

  f32x16 o0 = {}, o1 = {};
  f32x16 osacc = {};  // only [0] maintained/used
  float mrow = -3.0e38f;
  const f16x8 onesA = {(_Float16)1, (_Float16)1, (_Float16)1, (_Float16)1,
                       (_Float16)1, (_Float16)1, (_Float16)1, (_Float16)1};

  auto STAGE = [&](int bufi, int kv0) {
    gload_lds16(kg_r + (size_t)kv0 * CC + gc0 * 8, Ks[bufi] + dst0);
    gload_lds16(kg_r + (size_t)(kv0 + 32) * CC + gc1 * 8, Ks[bufi] + 2048 + dst0);
    gload_lds16(vt_r + kv0 + gc0 * 8, VTs[bufi] + dst0);
    gload_lds16(vt_r + 32 * TT + kv0 + gc1 * 8, VTs[bufi] + 2048 + dst0);
  };
  STAGE(0, kvbeg);
  __syncthreads();
  int cur = 0;
  for (int kv0 = kvbeg; kv0 < kvend; kv0 += 64) {
    if (kv0 + 64 < kvend) STAGE(cur ^ 1, kv0 + 64);
    const _Float16* Kc = Ks[cur];
    const _Float16* Vc = VTs[cur];
    #pragma unroll
    for (int sub = 0; sub < 2; ++sub) {
      f32x16 s = {};
      const int krow = (sub * 32 + l31) * 64;
      __builtin_amdgcn_s_setprio(1);
      #pragma unroll
      for (int ks = 0; ks < 4; ++ks) {
        f16x8 kf = *(const f16x8*)(Kc + krow + (((ks * 2 + hi) ^ swk[sub]) << 3));
        s = __builtin_amdgcn_mfma_f32_32x32x16_f16(kf, qf[ks], s, 0, 0, 0);
      }
      __builtin_amdgcn_s_setprio(0);
      float a0 = fmaxf(fmaxf(s[0], s[1]), s[2]);
      float a1 = fmaxf(fmaxf(s[3], s[4]), s[5]);
      float a2 = fmaxf(fmaxf(s[6], s[7]), s[8]);
      float a3 = fmaxf(fmaxf(s[9], s[10]), s[11]);
      float a4 = fmaxf(fmaxf(s[12], s[13]), s[14]);
      float m16v = fmaxf(fmaxf(fmaxf(a0, a1), a2), fmaxf(fmaxf(a3, a4), s[15]));
      int ok = (m16v <= mrow + 8.0f) ? 1 : 0;
      if (!__all(ok)) {
        float mo = fmaxf(m16v, __shfl_xor(m16v, 32));
        float mn = fmaxf(mrow, mo);
        float corr = exp2f(mrow - mn);
        mrow = mn;
        #pragma unroll
        for (int r = 0; r < 16; ++r) { o0[r] *= corr; o1[r] *= corr; }
        osacc[0] *= corr;
      }
      float p[16];
      #pragma unroll
      for (int r = 0; r < 16; ++r) p[r] = exp2f(s[r] - mrow);
      unsigned W[8], X[8];
      #pragma unroll
      for (int i = 0; i < 8; ++i) {
        W[i] = pkrtz(p[2 * i], p[2 * i + 1]);
        X[i] = __shfl_xor(W[i], 32);
      }
      union { unsigned u[4]; f16x8 v; } bp[2];
      #pragma unroll
      for (int s2 = 0; s2 < 2; ++s2) {
        bp[s2].u[0] = hi ? X[4 * s2 + 2] : W[4 * s2 + 0];
        bp[s2].u[1] = hi ? X[4 * s2 + 3] : W[4 * s2 + 1];
        bp[s2].u[2] = hi ? W[4 * s2 + 2] : X[4 * s2 + 0];
        bp[s2].u[3] = hi ? W[4 * s2 + 3] : X[4 * s2 + 1];
      }
      __builtin_amdgcn_s_setprio(1);
      #pragma unroll
      for (int s2 = 0; s2 < 2; ++s2) {
        int c = sub * 4 + s2 * 2 + hi;
        {
          f16x8 vf = *(const f16x8*)(Vc + l31 * 64 + ((c ^ swv[0]) << 3));
          o0 = __builtin_amdgcn_mfma_f32_32x32x16_f16(vf, bp[s2].v, o0, 0, 0, 0);
        }
        {
          f16x8 vf = *(const f16x8*)(Vc + (32 + l31) * 64 + ((c ^ swv[1]) << 3));
          o1 = __builtin_amdgcn_mfma_f32_32x32x16_f16(vf, bp[s2].v, o1, 0, 0, 0);
        }
        osacc = __builtin_amdgcn_mfma_f32_32x32x16_f16(onesA, bp[s2].v, osacc, 0, 0, 0);
      }
      __builtin_amdgcn_s_setprio(0);
    }
    __syncthreads();
    cur ^= 1;
  }
  float osum = osacc[0];  // full k-sum (MFMA reduces its whole K internally)
  float rinv = 1.0f / osum;
  const int qrow = qt0 + w * 32 + l31;
  // ---- write own partial (fp16) + L ----
  _Float16* ob = yp + (size_t)half * HALF_Y + ((size_t)(b * TT + qrow)) * CC + h * DD;
  f16x4 my0[4], my1[4];  // fp16-rounded own contribution (kept for blend)
  #pragma unroll
  for (int i = 0; i < 4; ++i) {
    int col0 = 8 * i + 4 * hi;
    uint2 v0, v1;
    v0.x = pkrtz(o0[4 * i + 0] * rinv, o0[4 * i + 1] * rinv);
    v0.y = pkrtz(o0[4 * i + 2] * rinv, o0[4 * i + 3] * rinv);
    v1.x = pkrtz(o1[4 * i + 0] * rinv, o1[4 * i + 1] * rinv);
    v1.y = pkrtz(o1[4 * i + 2] * rinv, o1[4 * i + 3] * rinv);
    my0[i] = *(f16x4*)&v0;
    my1[i] = *(f16x4*)&v1;
    *(uint2*)(ob + col0) = v0;
    *(uint2*)(ob + 32 + col0) = v1;
  }
  float Lme = mrow + log2f(osum);
  if (hi == 0)
    Lp[(size_t)half * HALF_L + ((size_t)b * HH + h) * TT + qrow] = Lme;
  // ---- last-finisher combine ----
  __threadfence();
  __shared__ int lastflag;
  const int pairid = blockIdx.x + 16 * blockIdx.y + 256 * b;
  if (t == 0) lastflag = atomicAdd(&flags[pairid], 1);
  __syncthreads();
  if (lastflag == 1) {
    __threadfence();
    float Lpn = Lp[(size_t)(1 - half) * HALF_L + ((size_t)b * HH + h) * TT + qrow];
    float m2 = fmaxf(Lme, Lpn);
    float wme = exp2f(Lme - m2), wp = exp2f(Lpn - m2);
    float rs2 = 1.0f / (wme + wp);
    wme *= rs2; wp *= rs2;
    const _Float16* pb = yp + (size_t)(1 - half) * HALF_Y +
                         ((size_t)(b * TT + qrow)) * CC + h * DD;
    _Float16* fb = att + ((size_t)(b * TT + qrow)) * CC + h * DD;
    #pragma unroll
    for (int i = 0; i < 4; ++i) {
      int col0 = 8 * i + 4 * hi;
      f16x4 p0 = *(const f16x4*)(pb + col0);
      f16x4 p1 = *(const f16x4*)(pb + 32 + col0);
      uint2 r0, r1;
      r0.x = pkrtz(wme * (float)my0[i][0] + wp * (float)p0[0],
                   wme * (float)my0[i][1] + wp * (float)p0[1]);
      r0.y = pkrtz(wme * (float)my0[i][2] + wp * (float)p0[2],
                   wme * (float)my0[i][3] + wp * (float)p0[3]);
      r1.x = pkrtz(wme * (float)my1[i][0] + wp * (float)p1[0],
                   wme * (float)my1[i][1] + wp * (float)p1[1]);
      r1.y = pkrtz(wme * (float)my1[i][2] + wp * (float)p1[2],
                   wme * (float)my1[i][3] + wp * (float)p1[3]);
      *(uint2*)(fb + col0) = r0;
      *(uint2*)(fb + 32 + col0) = r1;
    }
  }
}

extern "C" void kernel_launch(void* const* d_in, const int* in_sizes, int n_in,
                              void* d_out, int out_size, void* d_ws, size_t ws_size,
                              hipStream_t stream) {
  const float* x      = (const float*)d_in[0];
  const float* w_qkv  = (const float*)d_in[1];
  const float* b_qkv  = (const float*)d_in[2];
  const float* w_proj = (const float*)d_in[3];
  const float* b_proj = (const float*)d_in[4];
  const float* ln1_g  = (const float*)d_in[5];
  const float* ln1_b  = (const float*)d_in[6];
  const float* w_fc   = (const float*)d_in[7];
  const float* b_fc   = (const float*)d_in[8];
  const float* w_out  = (const float*)d_in[9];
  const float* b_out  = (const float*)d_in[10];
  const float* ln2_g  = (const float*)d_in[11];
  const float* ln2_b  = (const float*)d_in[12];

  char* ws = (char*)d_ws;
  _Float16* wqkv_t = (_Float16*)(ws);              // [3072,1024] 6291456
  _Float16* wproj_t= (_Float16*)(ws + 6291456);    // -> 8388608
  _Float16* wfc_t  = (_Float16*)(ws + 8388608);    // -> 16777216
  _Float16* wout_t = (_Float16*)(ws + 16777216);   // -> 25165824
  _Float16* hslot  = (_Float16*)(ws + 25165824);   // h -> att -> h2 (serial reuse)
  _Float16* qbuf   = (_Float16*)(ws + 33554432);
  _Float16* kbuf   = (_Float16*)(ws + 41943040);
  _Float16* vtbuf  = (_Float16*)(ws + 50331648);
  _Float16* tbuf   = (_Float16*)(ws + 33554432);   // [4096,4096] reuses q/k/vt (dead)
  float*    x1     = (float*)(ws + 67108864);      // -> 83886080
  _Float16* ypart  = (_Float16*)(ws + 83886080);   // -> 100663296
  float*    Lpart  = (float*)(ws + 100663296);     // -> 101187584
  int*      flags  = (int*)(ws + 101187584);       // 512 ints -> 101189632

  prep_all<<<16384, 256, 0, stream>>>(w_qkv, w_proj, w_fc, w_out, x, ln1_g, ln1_b,
                                      wqkv_t, wproj_t, wfc_t, wout_t, hslot, flags);
  gemm_qkv<<<768, 256, 0, stream>>>(hslot, wqkv_t, b_qkv, qbuf, kbuf, vtbuf);
  flash_attn<<<dim3(16, 16, 4), 256, 0, stream>>>(qbuf, kbuf, vtbuf, ypart, Lpart,
                                                  flags, hslot);
  gemm_bt<2, 1024, 1024, 64, 1><<<512, 256, 0, stream>>>(hslot, wproj_t, b_proj, x, x1, 16);
  ln_cast<<<4096, 256, 0, stream>>>(x1, ln2_g, ln2_b, hslot);
  gemm_bt<1, 4096, 1024, 128, 0><<<1024, 256, 0, stream>>>(hslot, wfc_t, b_fc, nullptr, tbuf, 32);
  gemm_bt<2, 1024, 4096, 64, 1><<<512, 256, 0, stream>>>(tbuf, wout_t, b_out, x1, (float*)d_out, 16);
}

// Round 19
// 277.164 us; speedup vs baseline: 1.7038x; 1.7038x over previous
//
#include <hip/hip_runtime.h>
#include <hip/hip_bf16.h>
#include <math.h>

#define DEVINL static __device__ __forceinline__

typedef _Float16 f16x8 __attribute__((ext_vector_type(8)));
typedef _Float16 f16x4 __attribute__((ext_vector_type(4)));
typedef float f32x4 __attribute__((ext_vector_type(4)));
typedef float f32x16 __attribute__((ext_vector_type(16)));

// B=2, T=2048, C=1024, H=16, D=64
constexpr int TT = 2048, CC = 1024, HH = 16, DD = 64;
constexpr int HALF_Y = 2 * TT * CC;
constexpr int HALF_L = 2 * HH * TT;

DEVINL void gload_lds16(const void* g, void* s) {
  __builtin_amdgcn_global_load_lds(
      (const __attribute__((address_space(1))) void*)g,
      (__attribute__((address_space(3))) void*)s, 16, 0, 0);
}

DEVINL unsigned pkrtz(float a, float b) {
  typedef __fp16 hf2 __attribute__((ext_vector_type(2)));
  union { hf2 h; unsigned u; } c;
  c.h = __builtin_amdgcn_cvt_pkrtz(a, b);
  return c.u;
}

DEVINL float fast_gelu(float v) {
  float z = v * (2.302208214f + 0.102945116f * v * v);
  return v * __builtin_amdgcn_rcpf(1.0f + exp2f(-z));
}

DEVINL int xcd_swizzle(int lid, int n) {
  int cpx = n >> 3;  // all grids are %8 == 0
  return (lid & 7) * cpx + (lid >> 3);
}

// ---- Fused: 4 weight transposes (fp32 [K,N] -> fp16 [N,K]) + LN1 ----
DEVINL void transpose_tile(const float* in, _Float16* out, int K, int N,
                           int bx, int by, int tid) {
  __shared__ float tile[32][33];
  int n0 = bx * 32, k0 = by * 32;
  int tx = tid & 31, ty = tid >> 5;
  #pragma unroll
  for (int i = 0; i < 32; i += 8)
    tile[ty + i][tx] = in[(size_t)(k0 + ty + i) * N + n0 + tx];
  __syncthreads();
  #pragma unroll
  for (int i = 0; i < 32; i += 8)
    out[(size_t)(n0 + ty + i) * K + k0 + tx] = (_Float16)tile[tx][ty + i];
}

DEVINL void ln_row(const float* x, const float* g, const float* bta,
                   _Float16* out, int row, int t) {
  float4 v = ((const float4*)(x + (size_t)row * CC))[t];
  float s = v.x + v.y + v.z + v.w;
  float s2 = v.x * v.x + v.y * v.y + v.z * v.z + v.w * v.w;
  #pragma unroll
  for (int o = 32; o >= 1; o >>= 1) { s += __shfl_xor(s, o); s2 += __shfl_xor(s2, o); }
  __shared__ float ss[4], ssq[4];
  int w = t >> 6;
  if ((t & 63) == 0) { ss[w] = s; ssq[w] = s2; }
  __syncthreads();
  s = ss[0] + ss[1] + ss[2] + ss[3];
  s2 = ssq[0] + ssq[1] + ssq[2] + ssq[3];
  float mu = s * (1.0f / CC);
  float rs = rsqrtf(s2 * (1.0f / CC) - mu * mu + 1e-5f);
  float4 gv = ((const float4*)g)[t];
  float4 bv = ((const float4*)bta)[t];
  f16x4 o4;
  o4[0] = (_Float16)((v.x - mu) * rs * gv.x + bv.x);
  o4[1] = (_Float16)((v.y - mu) * rs * gv.y + bv.y);
  o4[2] = (_Float16)((v.z - mu) * rs * gv.z + bv.z);
  o4[3] = (_Float16)((v.w - mu) * rs * gv.w + bv.w);
  ((f16x4*)(out + (size_t)row * CC))[t] = o4;
}

__global__ __launch_bounds__(256) void prep_all(
    const float* __restrict__ w_qkv, const float* __restrict__ w_proj,
    const float* __restrict__ w_fc, const float* __restrict__ w_out,
    const float* __restrict__ x, const float* __restrict__ ln1_g,
    const float* __restrict__ ln1_b,
    _Float16* __restrict__ wqkv_t, _Float16* __restrict__ wproj_t,
    _Float16* __restrict__ wfc_t, _Float16* __restrict__ wout_t,
    _Float16* __restrict__ h1) {
  int lid = blockIdx.x, t = threadIdx.x;
  if (lid < 3072) {
    transpose_tile(w_qkv, wqkv_t, 1024, 3072, lid % 96, lid / 96, t);
  } else if (lid < 4096) {
    int l = lid - 3072;
    transpose_tile(w_proj, wproj_t, 1024, 1024, l % 32, l / 32, t);
  } else if (lid < 8192) {
    int l = lid - 4096;
    transpose_tile(w_fc, wfc_t, 1024, 4096, l % 128, l / 128, t);
  } else if (lid < 12288) {
    int l = lid - 8192;
    transpose_tile(w_out, wout_t, 4096, 1024, l % 32, l / 32, t);
  } else {
    ln_row(x, ln1_g, ln1_b, h1, lid - 12288, t);
  }
}

__global__ __launch_bounds__(256) void ln_cast(
    const float* __restrict__ x, const float* __restrict__ g,
    const float* __restrict__ bta, _Float16* __restrict__ out) {
  ln_row(x, g, bta, out, blockIdx.x, threadIdx.x);
}

// ---- GEMM (verified structure): BK=64. 1D grid + XCD swizzle.
// BN=128: 4 waves 2x2 (64x64 each). BN=64: 4 waves 4x1 (32x64 each).
// DBUF=1: double-buffered LDS + counted vmcnt. EPI 1: GELU. EPI 2: +res fp32.
template <int EPI, int N, int K, int BN, int DBUF>
__global__ __launch_bounds__(256) void gemm_bt(
    const _Float16* __restrict__ A, const _Float16* __restrict__ Bt,
    const float* __restrict__ bias, const float* __restrict__ res,
    void* __restrict__ outp, int nbx) {
  constexpr int NWN = BN / 64;
  constexpr int MI = 2 * NWN;
  constexpr int NB = DBUF ? 2 : 1;
  constexpr int NLOADS = 4 + BN / 32;
  __shared__ __align__(16) _Float16 As[NB][128 * 64];
  __shared__ __align__(16) _Float16 Bs[NB][BN * 64];
  const int swz = xcd_swizzle(blockIdx.x, gridDim.x);
  const int bm0 = (swz / nbx) * 128, bn0 = (swz % nbx) * BN;
  const int t = threadIdx.x, w = t >> 6, l = t & 63, lg = l >> 4, lr = l & 15;
  const int wr = w / NWN, wc = w % NWN;
  const int srow = t >> 3, sc = t & 7;
  f32x4 acc[MI][4] = {};

  auto STAGE = [&](int bi, int k0) {
    #pragma unroll
    for (int q = 0; q < 4; ++q) {
      int row = q * 32 + srow;
      int gc = sc ^ (row & 7);  // inverse-swizzle global source (rule 21)
      gload_lds16(A + (size_t)(bm0 + row) * K + k0 + gc * 8, As[bi] + row * 64 + sc * 8);
    }
    #pragma unroll
    for (int q = 0; q < BN / 32; ++q) {
      int row = q * 32 + srow;
      int gc = sc ^ (row & 7);
      gload_lds16(Bt + (size_t)(bn0 + row) * K + k0 + gc * 8, Bs[bi] + row * 64 + sc * 8);
    }
  };
  auto COMPUTE = [&](const _Float16* Ac, const _Float16* Bc) {
    #pragma unroll
    for (int ks = 0; ks < 2; ++ks) {
      f16x8 af[MI], bfr[4];
      #pragma unroll
      for (int mi = 0; mi < MI; ++mi) {
        int row = wr * (16 * MI) + mi * 16 + lr;
        af[mi] = *(const f16x8*)(Ac + row * 64 + (((ks * 4 + lg) ^ (row & 7)) << 3));
      }
      #pragma unroll
      for (int ni = 0; ni < 4; ++ni) {
        int row = wc * 64 + ni * 16 + lr;
        bfr[ni] = *(const f16x8*)(Bc + row * 64 + (((ks * 4 + lg) ^ (row & 7)) << 3));
      }
      #pragma unroll
      for (int mi = 0; mi < MI; ++mi)
        #pragma unroll
        for (int ni = 0; ni < 4; ++ni)
          acc[mi][ni] = __builtin_amdgcn_mfma_f32_16x16x32_f16(af[mi], bfr[ni], acc[mi][ni], 0, 0, 0);
    }
  };

  if constexpr (DBUF) {
    STAGE(0, 0);
    int cur = 0;
    for (int k0 = 0; k0 < K; k0 += 64) {
      if (k0 + 64 < K) {
        STAGE(cur ^ 1, k0 + 64);
        asm volatile("s_waitcnt vmcnt(%0)" :: "i"(NLOADS) : "memory");
      } else {
        asm volatile("s_waitcnt vmcnt(0)" ::: "memory");
      }
      __builtin_amdgcn_s_barrier();
      COMPUTE(As[cur], Bs[cur]);
      __builtin_amdgcn_s_barrier();
      cur ^= 1;
    }
  } else {
    for (int k0 = 0; k0 < K; k0 += 64) {
      STAGE(0, k0);
      __syncthreads();
      COMPUTE(As[0], Bs[0]);
      __syncthreads();
    }
  }

  #pragma unroll
  for (int mi = 0; mi < MI; ++mi) {
    #pragma unroll
    for (int ni = 0; ni < 4; ++ni) {
      int gc = bn0 + wc * 64 + ni * 16 + lr;
      float bv = bias[gc];
      #pragma unroll
      for (int r = 0; r < 4; ++r) {
        int gr = bm0 + wr * (16 * MI) + mi * 16 + lg * 4 + r;
        float v = acc[mi][ni][r] + bv;
        if constexpr (EPI == 1) {
          ((_Float16*)outp)[(size_t)gr * N + gc] = (_Float16)fast_gelu(v);
        } else {
          ((float*)outp)[(size_t)gr * N + gc] = res[(size_t)gr * N + gc] + v;
        }
      }
    }
  }
}

// ---- QKV GEMM: BK=64 single-buffer, XCD swizzle ----
__global__ __launch_bounds__(256) void gemm_qkv(
    const _Float16* __restrict__ A, const _Float16* __restrict__ Bt,
    const float* __restrict__ bias,
    _Float16* __restrict__ qo, _Float16* __restrict__ ko,
    _Float16* __restrict__ vt) {
  __shared__ __align__(16) _Float16 As[128 * 64];
  __shared__ __align__(16) _Float16 Bs[128 * 64];
  const int swz = xcd_swizzle(blockIdx.x, gridDim.x);
  const int bm0 = (swz / 24) * 128, bn0 = (swz % 24) * 128;
  const int t = threadIdx.x, w = t >> 6, l = t & 63, lg = l >> 4, lr = l & 15;
  const int wr = w >> 1, wc = w & 1;
  const int srow = t >> 3, sc = t & 7;
  f32x4 acc[4][4] = {};
  for (int k0 = 0; k0 < 1024; k0 += 64) {
    #pragma unroll
    for (int q = 0; q < 4; ++q) {
      int row = q * 32 + srow;
      int gc = sc ^ (row & 7);
      gload_lds16(A + (size_t)(bm0 + row) * 1024 + k0 + gc * 8, As + row * 64 + sc * 8);
      gload_lds16(Bt + (size_t)(bn0 + row) * 1024 + k0 + gc * 8, Bs + row * 64 + sc * 8);
    }
    __syncthreads();
    #pragma unroll
    for (int ks = 0; ks < 2; ++ks) {
      f16x8 af[4], bfr[4];
      #pragma unroll
      for (int mi = 0; mi < 4; ++mi) {
        int row = wr * 64 + mi * 16 + lr;
        af[mi] = *(const f16x8*)(As + row * 64 + (((ks * 4 + lg) ^ (row & 7)) << 3));
      }
      #pragma unroll
      for (int ni = 0; ni < 4; ++ni) {
        int row = wc * 64 + ni * 16 + lr;
        bfr[ni] = *(const f16x8*)(Bs + row * 64 + (((ks * 4 + lg) ^ (row & 7)) << 3));
      }
      #pragma unroll
      for (int mi = 0; mi < 4; ++mi)
        #pragma unroll
        for (int ni = 0; ni < 4; ++ni)
          acc[mi][ni] = __builtin_amdgcn_mfma_f32_16x16x32_f16(af[mi], bfr[ni], acc[mi][ni], 0, 0, 0);
    }
    __syncthreads();
  }
  const float QSCL = 0.125f * 1.44269504f;
  #pragma unroll
  for (int mi = 0; mi < 4; ++mi) {
    #pragma unroll
    for (int ni = 0; ni < 4; ++ni) {
      int gc = bn0 + wc * 64 + ni * 16 + lr;
      float bv = bias[gc];
      int sec = gc >> 10, cc = gc & 1023;
      #pragma unroll
      for (int r = 0; r < 4; ++r) {
        int gr = bm0 + wr * 64 + mi * 16 + lg * 4 + r;
        float v = acc[mi][ni][r] + bv;
        if (sec == 0) {
          qo[(size_t)gr * 1024 + cc] = (_Float16)(v * QSCL);
        } else if (sec == 1) {
          ko[(size_t)gr * 1024 + cc] = (_Float16)v;
        } else {
          int hh = cc >> 6, dd = cc & 63;
          int bb = gr >> 11, tk = gr & (TT - 1);
          vt[(((size_t)bb * HH + hh) * DD + dd) * TT + tk] = (_Float16)v;
        }
      }
    }
  }
}

// ---- Flash attention v6 (verified): 32x32 swapped MFMA + split-KV;
// psum via ones-MFMA (osacc[0] = full k-sum), shfl_xor P-pack. ----
__global__ __launch_bounds__(256, 4) void flash_attn(
    const _Float16* __restrict__ qg, const _Float16* __restrict__ kg,
    const _Float16* __restrict__ vt, _Float16* __restrict__ yp,
    float* __restrict__ Lp) {
  const int qt0 = blockIdx.x * 128, h = blockIdx.y;
  const int b = blockIdx.z & 1, half = blockIdx.z >> 1;
  const int kvbeg = half * (TT / 2), kvend = kvbeg + TT / 2;
  const int t = threadIdx.x, w = t >> 6, l = t & 63;
  const int l31 = l & 31, hi = l >> 5;
  __shared__ __align__(16) _Float16 Ks[2][64 * 64];
  __shared__ __align__(16) _Float16 VTs[2][64 * 64];
  const int srow = t >> 3, sc = t & 7;
  const int gc0 = sc ^ (srow & 7) ^ ((srow >> 3) & 7);
  const int gc1 = sc ^ (srow & 7) ^ (((srow >> 3) + 4) & 7);
  const _Float16* kg_r = kg + ((size_t)b * TT + srow) * CC + h * DD;
  const _Float16* vt_r = vt + (((size_t)b * HH + h) * DD + srow) * TT;
  const int dst0 = srow * 64 + sc * 8;

  f16x8 qf[4];
  {
    const _Float16* qp = qg + ((size_t)(b * TT + qt0 + w * 32 + l31)) * CC + h * DD + hi * 8;
    #pragma unroll
    for (int ks = 0; ks < 4; ++ks) qf[ks] = *(const f16x8*)(qp + ks * 16);
  }
  const int rx = l31 & 7, ry = (l31 >> 3) & 7;
  int swk[2], swv[2];
  #pragma unroll
  for (int sub = 0; sub < 2; ++sub) swk[sub] = rx ^ ((sub * 4 + ry) & 7);
  swv[0] = rx ^ ry;
  swv[1] = rx ^ ((4 + ry) & 7);

  f32x16 o0 = {}, o1 = {};
  f32x16 osacc = {};  // only [0] maintained/used
  float mrow = -3.0e38f;
  const f16x8 onesA = {(_Float16)1, (_Float16)1, (_Float16)1, (_Float16)1,
                       (_Float16)1, (_Float16)1, (_Float16)1, (_Float16)1};

  auto STAGE = [&](int bufi, int kv0) {
    gload_lds16(kg_r + (size_t)kv0 * CC + gc0 * 8, Ks[bufi] + dst0);
    gload_lds16(kg_r + (size_t)(kv0 + 32) * CC + gc1 * 8, Ks[bufi] + 2048 + dst0);
    gload_lds16(vt_r + kv0 + gc0 * 8, VTs[bufi] + dst0);
    gload_lds16(vt_r + 32 * TT + kv0 + gc1 * 8, VTs[bufi] + 2048 + dst0);
  };
  STAGE(0, kvbeg);
  __syncthreads();
  int cur = 0;
  for (int kv0 = kvbeg; kv0 < kvend; kv0 += 64) {
    if (kv0 + 64 < kvend) STAGE(cur ^ 1, kv0 + 64);
    const _Float16* Kc = Ks[cur];
    const _Float16* Vc = VTs[cur];
    #pragma unroll
    for (int sub = 0; sub < 2; ++sub) {
      f32x16 s = {};
      const int krow = (sub * 32 + l31) * 64;
      __builtin_amdgcn_s_setprio(1);
      #pragma unroll
      for (int ks = 0; ks < 4; ++ks) {
        f16x8 kf = *(const f16x8*)(Kc + krow + (((ks * 2 + hi) ^ swk[sub]) << 3));
        s = __builtin_amdgcn_mfma_f32_32x32x16_f16(kf, qf[ks], s, 0, 0, 0);
      }
      __builtin_amdgcn_s_setprio(0);
      float a0 = fmaxf(fmaxf(s[0], s[1]), s[2]);
      float a1 = fmaxf(fmaxf(s[3], s[4]), s[5]);
      float a2 = fmaxf(fmaxf(s[6], s[7]), s[8]);
      float a3 = fmaxf(fmaxf(s[9], s[10]), s[11]);
      float a4 = fmaxf(fmaxf(s[12], s[13]), s[14]);
      float m16v = fmaxf(fmaxf(fmaxf(a0, a1), a2), fmaxf(fmaxf(a3, a4), s[15]));
      int ok = (m16v <= mrow + 8.0f) ? 1 : 0;
      if (!__all(ok)) {
        float mo = fmaxf(m16v, __shfl_xor(m16v, 32));
        float mn = fmaxf(mrow, mo);
        float corr = exp2f(mrow - mn);
        mrow = mn;
        #pragma unroll
        for (int r = 0; r < 16; ++r) { o0[r] *= corr; o1[r] *= corr; }
        osacc[0] *= corr;
      }
      float p[16];
      #pragma unroll
      for (int r = 0; r < 16; ++r) p[r] = exp2f(s[r] - mrow);
      unsigned W[8], X[8];
      #pragma unroll
      for (int i = 0; i < 8; ++i) {
        W[i] = pkrtz(p[2 * i], p[2 * i + 1]);
        X[i] = __shfl_xor(W[i], 32);
      }
      union { unsigned u[4]; f16x8 v; } bp[2];
      #pragma unroll
      for (int s2 = 0; s2 < 2; ++s2) {
        bp[s2].u[0] = hi ? X[4 * s2 + 2] : W[4 * s2 + 0];
        bp[s2].u[1] = hi ? X[4 * s2 + 3] : W[4 * s2 + 1];
        bp[s2].u[2] = hi ? W[4 * s2 + 2] : X[4 * s2 + 0];
        bp[s2].u[3] = hi ? W[4 * s2 + 3] : X[4 * s2 + 1];
      }
      __builtin_amdgcn_s_setprio(1);
      #pragma unroll
      for (int s2 = 0; s2 < 2; ++s2) {
        int c = sub * 4 + s2 * 2 + hi;
        {
          f16x8 vf = *(const f16x8*)(Vc + l31 * 64 + ((c ^ swv[0]) << 3));
          o0 = __builtin_amdgcn_mfma_f32_32x32x16_f16(vf, bp[s2].v, o0, 0, 0, 0);
        }
        {
          f16x8 vf = *(const f16x8*)(Vc + (32 + l31) * 64 + ((c ^ swv[1]) << 3));
          o1 = __builtin_amdgcn_mfma_f32_32x32x16_f16(vf, bp[s2].v, o1, 0, 0, 0);
        }
        osacc = __builtin_amdgcn_mfma_f32_32x32x16_f16(onesA, bp[s2].v, osacc, 0, 0, 0);
      }
      __builtin_amdgcn_s_setprio(0);
    }
    __syncthreads();
    cur ^= 1;
  }
  float osum = osacc[0];  // full k-sum (MFMA reduces its whole K internally)
  float rinv = 1.0f / osum;
  const int qrow = qt0 + w * 32 + l31;
  _Float16* ob = yp + (size_t)half * HALF_Y + ((size_t)(b * TT + qrow)) * CC + h * DD;
  #pragma unroll
  for (int i = 0; i < 4; ++i) {
    int col0 = 8 * i + 4 * hi;
    uint2 v0, v1;
    v0.x = pkrtz(o0[4 * i + 0] * rinv, o0[4 * i + 1] * rinv);
    v0.y = pkrtz(o0[4 * i + 2] * rinv, o0[4 * i + 3] * rinv);
    v1.x = pkrtz(o1[4 * i + 0] * rinv, o1[4 * i + 1] * rinv);
    v1.y = pkrtz(o1[4 * i + 2] * rinv, o1[4 * i + 3] * rinv);
    *(uint2*)(ob + col0) = v0;
    *(uint2*)(ob + 32 + col0) = v1;
  }
  if (hi == 0)
    Lp[(size_t)half * HALF_L + ((size_t)b * HH + h) * TT + qrow] =
        mrow + log2f(osum);
}

// ---- combine the two KV-half partials ----
__global__ __launch_bounds__(256) void attn_combine(
    const _Float16* __restrict__ yp, const float* __restrict__ Lp,
    _Float16* __restrict__ att) {
  int bt = blockIdx.x;
  int b = bt >> 11, tt = bt & (TT - 1);
  int tid = threadIdx.x;
  int h = tid >> 4;
  size_t li = ((size_t)b * HH + h) * TT + tt;
  float L0 = Lp[li], L1 = Lp[HALF_L + li];
  float m = fmaxf(L0, L1);
  float w0 = exp2f(L0 - m), w1 = exp2f(L1 - m);
  float rs = 1.0f / (w0 + w1);
  w0 *= rs; w1 *= rs;
  f16x4 a = ((const f16x4*)(yp + (size_t)bt * CC))[tid];
  f16x4 c = ((const f16x4*)(yp + HALF_Y + (size_t)bt * CC))[tid];
  f16x4 o;
  #pragma unroll
  for (int i = 0; i < 4; ++i)
    o[i] = (_Float16)(w0 * (float)a[i] + w1 * (float)c[i]);
  ((f16x4*)(att + (size_t)bt * CC))[tid] = o;
}

extern "C" void kernel_launch(void* const* d_in, const int* in_sizes, int n_in,
                              void* d_out, int out_size, void* d_ws, size_t ws_size,
                              hipStream_t stream) {
  const float* x      = (const float*)d_in[0];
  const float* w_qkv  = (const float*)d_in[1];
  const float* b_qkv  = (const float*)d_in[2];
  const float* w_proj = (const float*)d_in[3];
  const float* b_proj = (const float*)d_in[4];
  const float* ln1_g  = (const float*)d_in[5];
  const float* ln1_b  = (const float*)d_in[6];
  const float* w_fc   = (const float*)d_in[7];
  const float* b_fc   = (const float*)d_in[8];
  const float* w_out  = (const float*)d_in[9];
  const float* b_out  = (const float*)d_in[10];
  const float* ln2_g  = (const float*)d_in[11];
  const float* ln2_b  = (const float*)d_in[12];

  char* ws = (char*)d_ws;
  _Float16* wqkv_t = (_Float16*)(ws);              // [3072,1024] 6291456
  _Float16* wproj_t= (_Float16*)(ws + 6291456);    // -> 8388608
  _Float16* wfc_t  = (_Float16*)(ws + 8388608);    // -> 16777216
  _Float16* wout_t = (_Float16*)(ws + 16777216);   // -> 25165824
  _Float16* hslot  = (_Float16*)(ws + 25165824);   // h -> att -> h2 (serial reuse)
  _Float16* qbuf   = (_Float16*)(ws + 33554432);
  _Float16* kbuf   = (_Float16*)(ws + 41943040);
  _Float16* vtbuf  = (_Float16*)(ws + 50331648);
  _Float16* tbuf   = (_Float16*)(ws + 33554432);   // [4096,4096] reuses q/k/vt (dead)
  float*    x1     = (float*)(ws + 67108864);      // -> 83886080
  _Float16* ypart  = (_Float16*)(ws + 83886080);   // -> 100663296
  float*    Lpart  = (float*)(ws + 100663296);     // -> 101187584

  prep_all<<<16384, 256, 0, stream>>>(w_qkv, w_proj, w_fc, w_out, x, ln1_g, ln1_b,
                                      wqkv_t, wproj_t, wfc_t, wout_t, hslot);
  gemm_qkv<<<768, 256, 0, stream>>>(hslot, wqkv_t, b_qkv, qbuf, kbuf, vtbuf);
  flash_attn<<<dim3(16, 16, 4), 256, 0, stream>>>(qbuf, kbuf, vtbuf, ypart, Lpart);
  attn_combine<<<4096, 256, 0, stream>>>(ypart, Lpart, hslot);
  gemm_bt<2, 1024, 1024, 64, 1><<<512, 256, 0, stream>>>(hslot, wproj_t, b_proj, x, x1, 16);
  ln_cast<<<4096, 256, 0, stream>>>(x1, ln2_g, ln2_b, hslot);
  gemm_bt<1, 4096, 1024, 128, 0><<<1024, 256, 0, stream>>>(hslot, wfc_t, b_fc, nullptr, tbuf, 32);
  gemm_bt<2, 1024, 4096, 64, 1><<<512, 256, 0, stream>>>(tbuf, wout_t, b_out, x1, (float*)d_out, 16);
}